// Round 1
// baseline (763.433 us; speedup 1.0000x reference)
//
#include <hip/hip_runtime.h>
#include <math.h>

// Problem constants
// x: (8, 32, 64, 64, 64) fp32 ; weight: (32cin, 32cout, 3,3,3) ; bias,scale: (32,)
// pooled: (8, 32, 32, 32, 32) in d_ws ; S[256] sums after pooled in d_ws
// out: (8, 32, 64, 64, 64) fp32

constexpr int CIN_CHUNK = 8;

// ---------------- Pass 1: avg-pool 2x2x2 (+ zero the softmax sums) ----------------
__global__ void pool_kernel(const float* __restrict__ x, float* __restrict__ p,
                            float* __restrict__ S) {
    if (blockIdx.x == 0 && threadIdx.x < 256) S[threadIdx.x] = 0.f;
    int n = blockIdx.x * 256 + threadIdx.x;       // 0 .. 8*32*32768-1 (= 2^23)
    if (n >= 8 * 32 * 32768) return;
    int w = n & 31;
    int h = (n >> 5) & 31;
    int d = (n >> 10) & 31;
    int c = (n >> 15) & 31;
    int b = n >> 20;
    const float* xb = x + (((size_t)((b * 32 + c) * 64 + 2 * d) * 64 + 2 * h) * 64 + 2 * w);
    float2 a0 = *(const float2*)(xb);
    float2 a1 = *(const float2*)(xb + 64);
    float2 a2 = *(const float2*)(xb + 4096);
    float2 a3 = *(const float2*)(xb + 4096 + 64);
    float s = a0.x + a0.y + a1.x + a1.y + a2.x + a2.y + a3.x + a3.y;
    p[n] = s * 0.125f;
}

// ---------------- Pass 2: conv-transpose + bias + clamp + exp + partial sums ------
// Block: (od' , oh'-tile of 4, b). 512 threads = (cout 32) x (tg 16).
// tg: wb = (tg&7)*4  (w' segment of 4), R0 = (tg>>3)*2 (2 oh' rows).
// Each thread: acc[pd][ph][pw][rr][i] = 2*2*2*2*4 = 64 outputs.
__global__ __launch_bounds__(512, 4)
void convt_kernel(const float* __restrict__ P, const float* __restrict__ W,
                  const float* __restrict__ bias, float* __restrict__ out,
                  float* __restrict__ S) {
    __shared__ float Pl[CIN_CHUNK][2][5][36];  // [cin][plane][row][w(33 used)]
    __shared__ float Wl[CIN_CHUNK][32][28];    // [cin][cout][tap(27 used)]

    const int odp = blockIdx.x;        // od' 0..31
    const int ohb = blockIdx.y * 4;    // oh' base
    const int b   = blockIdx.z;
    const int tid = threadIdx.x;
    const int cout = tid >> 4;
    const int tg   = tid & 15;
    const int wb = (tg & 7) * 4;
    const int R0 = (tg >> 3) * 2;

    float acc[2][2][2][2][4];
#pragma unroll
    for (int a0 = 0; a0 < 2; ++a0)
#pragma unroll
        for (int a1 = 0; a1 < 2; ++a1)
#pragma unroll
            for (int a2 = 0; a2 < 2; ++a2)
#pragma unroll
                for (int a3 = 0; a3 < 2; ++a3)
#pragma unroll
                    for (int a4 = 0; a4 < 4; ++a4) acc[a0][a1][a2][a3][a4] = 0.f;

    for (int cc = 0; cc < 32; cc += CIN_CHUNK) {
        __syncthreads();
        // stage pooled tile: cin_chunk x 2 planes x 5 rows x 33 w, zero-padded
        for (int idx = tid; idx < CIN_CHUNK * 2 * 5 * 33; idx += 512) {
            int w = idx % 33;
            int t1 = idx / 33;
            int r = t1 % 5;
            int t2 = t1 / 5;
            int pl = t2 & 1;
            int c = t2 >> 1;
            int id = odp + pl;
            int ih = ohb + r;
            float v = 0.f;
            if (id < 32 && ih < 32 && w < 32)
                v = P[(((size_t)((b * 32 + cc + c) * 32) + id) * 32 + ih) * 32 + w];
            Pl[c][pl][r][w] = v;
        }
        // stage weights: contiguous in global ([cin][cout][27])
        for (int idx = tid; idx < CIN_CHUNK * 32 * 27; idx += 512) {
            int t = idx % 27;
            int t1 = idx / 27;
            int co = t1 & 31;
            int c = t1 >> 5;
            Wl[c][co][t] = W[(size_t)cc * 864 + idx];
            (void)co; (void)t; (void)c;
        }
        __syncthreads();

        for (int c = 0; c < CIN_CHUNK; ++c) {
            float pr[3][5];
            // ---- plane 1 (id = od'+1): taps kd==0 (t = 0..8) ----
#pragma unroll
            for (int j = 0; j < 3; ++j) {
                const float* base = &Pl[c][1][R0 + j][wb];
                float4 v4 = *(const float4*)base;
                pr[j][0] = v4.x; pr[j][1] = v4.y; pr[j][2] = v4.z; pr[j][3] = v4.w;
                pr[j][4] = base[4];
            }
#pragma unroll
            for (int t = 0; t < 9; ++t) {
                const int kh = t / 3, kw = t % 3;
                const int pd = 1;                       // kd==0 -> odd od
                const int ph = (kh == 1) ? 0 : 1, dh = (kh == 0) ? 1 : 0;
                const int pw = (kw == 1) ? 0 : 1, dw = (kw == 0) ? 1 : 0;
                float wv = Wl[c][cout][t];
#pragma unroll
                for (int rr = 0; rr < 2; ++rr)
#pragma unroll
                    for (int i = 0; i < 4; ++i)
                        acc[pd][ph][pw][rr][i] += pr[rr + dh][i + dw] * wv;
            }
            // ---- plane 0 (id = od'): taps kd==1 (pd=0) and kd==2 (pd=1), t = 9..26 ----
#pragma unroll
            for (int j = 0; j < 3; ++j) {
                const float* base = &Pl[c][0][R0 + j][wb];
                float4 v4 = *(const float4*)base;
                pr[j][0] = v4.x; pr[j][1] = v4.y; pr[j][2] = v4.z; pr[j][3] = v4.w;
                pr[j][4] = base[4];
            }
#pragma unroll
            for (int t = 9; t < 27; ++t) {
                const int kd = t / 9, kh = (t / 3) % 3, kw = t % 3;
                const int pd = (kd == 1) ? 0 : 1;
                const int ph = (kh == 1) ? 0 : 1, dh = (kh == 0) ? 1 : 0;
                const int pw = (kw == 1) ? 0 : 1, dw = (kw == 0) ? 1 : 0;
                float wv = Wl[c][cout][t];
#pragma unroll
                for (int rr = 0; rr < 2; ++rr)
#pragma unroll
                    for (int i = 0; i < 4; ++i)
                        acc[pd][ph][pw][rr][i] += pr[rr + dh][i + dw] * wv;
            }
        }
    }

    // ---- epilogue: bias, clamp, exp, store, partial softmax sums ----
    const float bv = bias[cout];
    float lsum = 0.f;
    float* ob = out + ((size_t)(b * 32 + cout) * 262144);
#pragma unroll
    for (int pd = 0; pd < 2; ++pd) {
        const int od = 2 * odp + pd;
#pragma unroll
        for (int rr = 0; rr < 2; ++rr) {
#pragma unroll
            for (int ph = 0; ph < 2; ++ph) {
                const int oh = 2 * (ohb + R0 + rr) + ph;
                float v[8];
#pragma unroll
                for (int i = 0; i < 4; ++i)
#pragma unroll
                    for (int pw = 0; pw < 2; ++pw) {
                        float y = acc[pd][ph][pw][rr][i] + bv;
                        y = fminf(fmaxf(y, 0.f), 1.f);
                        float e = __expf(y);
                        lsum += e;
                        v[2 * i + pw] = e;
                    }
                float* dst = ob + (size_t)od * 4096 + oh * 64 + 2 * wb;
                *(float4*)dst = make_float4(v[0], v[1], v[2], v[3]);
                *(float4*)(dst + 4) = make_float4(v[4], v[5], v[6], v[7]);
            }
        }
    }
    // reduce over the 16 consecutive lanes sharing this cout
#pragma unroll
    for (int off = 1; off < 16; off <<= 1) lsum += __shfl_xor(lsum, off, 64);
    if (tg == 0) atomicAdd(&S[b * 32 + cout], lsum);
}

// ---------------- Pass 3: out *= scale[c] / S[b,c] --------------------------------
__global__ void scale_kernel(float* __restrict__ out, const float* __restrict__ S,
                             const float* __restrict__ scale) {
    const long long total4 = 16777216LL;  // 67108864 / 4
    long long stride = (long long)gridDim.x * blockDim.x;
    for (long long f = (long long)blockIdx.x * blockDim.x + threadIdx.x; f < total4;
         f += stride) {
        int bc = (int)(f >> 16);          // 65536 float4 per (b,c)
        int c = bc & 31;
        float m = scale[c] / S[bc];
        float4* p = (float4*)out + f;
        float4 v = *p;
        v.x *= m; v.y *= m; v.z *= m; v.w *= m;
        *p = v;
    }
}

extern "C" void kernel_launch(void* const* d_in, const int* in_sizes, int n_in,
                              void* d_out, int out_size, void* d_ws, size_t ws_size,
                              hipStream_t stream) {
    const float* x     = (const float*)d_in[0];
    const float* W     = (const float*)d_in[1];
    const float* bias  = (const float*)d_in[2];
    const float* scale = (const float*)d_in[3];
    float* out = (float*)d_out;
    float* pooled = (float*)d_ws;                    // 8*32*32768 floats = 32 MiB
    float* S = (float*)d_ws + 8 * 32 * 32768;        // 256 floats

    pool_kernel<<<32768, 256, 0, stream>>>(x, pooled, S);
    convt_kernel<<<dim3(32, 8, 8), 512, 0, stream>>>(pooled, W, bias, out, S);
    scale_kernel<<<4096, 256, 0, stream>>>(out, S, scale);
}